// Round 1
// 232.835 us; speedup vs baseline: 1.0152x; 1.0152x over previous
//
#include <hip/hip_runtime.h>
#include <hip/hip_bf16.h>

// ---- problem constants ----
#define IN_F   3072
#define OUT_F  12288
#define M_ROWS 64
#define NBLK   96                 // IN_F / 32 k-blocks
#define SLAB   256                // k ints per slab per row (1 KB/row)
#define NSLAB  (IN_F / SLAB)      // 12
#define SSTEP  (SLAB / 32)        // 8 MFMA k-steps per slab

typedef short bf16x8 __attribute__((ext_vector_type(8)));   // 8 bf16 = 4 VGPRs
typedef float f32x4  __attribute__((ext_vector_type(4)));

__device__ __forceinline__ short f2bf(float f) {
    union { __hip_bfloat16 h; short s; } u;
    u.h = __float2bfloat16(f);
    return u.s;
}

// async global->LDS, 16 B per lane; LDS dest = wave-uniform base + lane*16
__device__ __forceinline__ void glds16(const void* g, void* l) {
    __builtin_amdgcn_global_load_lds(
        (const __attribute__((address_space(1))) unsigned int*)g,
        (__attribute__((address_space(3))) unsigned int*)l,
        16, 0, 0);
}

// Pack x (64 x 3072 f32) into MFMA A-fragment order, bf16 (unchanged).
// Fragment index p = (ks_global*4 + mt)*64 + lane; lane holds
// x[mt*16 + (lane&15)][ks*32 + (lane>>4)*8 + j], j=0..7.
__global__ void pack_x(const float* __restrict__ x, short* __restrict__ xp) {
    int p   = blockIdx.x * 256 + threadIdx.x;   // 0..24575
    int ks  = p >> 8;                           // 0..95
    int rem = p & 255;
    int mt  = rem >> 6;
    int l   = rem & 63;
    int m   = mt * 16 + (l & 15);
    int k0  = ks * 32 + (l >> 4) * 8;
    const float4* src = reinterpret_cast<const float4*>(x + m * IN_F + k0);
    float4 a = src[0];
    float4 b = src[1];
    bf16x8 v;
    v[0] = f2bf(a.x); v[1] = f2bf(a.y); v[2] = f2bf(a.z); v[3] = f2bf(a.w);
    v[4] = f2bf(b.x); v[5] = f2bf(b.y); v[6] = f2bf(b.z); v[7] = f2bf(b.w);
    *reinterpret_cast<bf16x8*>(xp + (long)p * 8) = v;
}

// Fused GEMM v2: block = 16 output cols (W rows), 4 waves split M (16 x-rows
// each, full K per wave -> no cross-wave reduce). W codes staged to LDS in
// 1KB-contiguous-per-row slabs via global_load_lds (pre-swizzled source,
// XOR-swizzled ds_read -> bank-conflict-free). Double-buffered slabs.
// grid = 768 blocks = 3 blocks/CU, 12 waves/CU; LDS = 32K + 6.2K.
__global__ __launch_bounds__(256) void gemm(const int*   __restrict__ wq,
                                            const float* __restrict__ wsc,
                                            const short* __restrict__ xp,
                                            const int*   __restrict__ bq,
                                            const float* __restrict__ bs,
                                            float*       __restrict__ out) {
    __shared__ int   s_w[2][16][SLAB];     // 2 x 16 rows x 1KB = 32 KB
    __shared__ float s_sc[16 * 97];        // 16 cols x 96 k-blocks, pad 97

    int tid = threadIdx.x;
    int cb  = blockIdx.x * 16;     // col base (= W row base)
    int w   = tid >> 6;            // wave id = M tile (x rows 16w..16w+15)
    int l   = tid & 63;
    int ro  = l & 15;              // output col within tile / W row within tile
    int kq  = l >> 4;              // k quarter within 32-k step

    // Stage scales: 16 rows x 96 k-blocks (coalesced-ish, once per block)
    for (int i = tid; i < 16 * NBLK; i += 256) {
        int r = i / NBLK;
        int c = i - r * NBLK;
        s_sc[r * 97 + c] = wsc[(cb + r) * NBLK + c];
    }

    int   col  = cb + ro;
    float bias = (float)(bq[col] - 128) * bs[col >> 5];

    // Per-lane pre-swizzled global sources: wave w stages rows 4w..4w+3.
    // LDS[r][b] = W[r][b ^ ((r&7)<<4)]  (16B-chunk XOR involution)
    const char* gsrc[4];
#pragma unroll
    for (int i = 0; i < 4; ++i) {
        int r = w * 4 + i;
        gsrc[i] = (const char*)(wq + (long)(cb + r) * IN_F) + ((l ^ (r & 7)) << 4);
    }

    // prologue: stage slab 0 into buffer 0
#pragma unroll
    for (int i = 0; i < 4; ++i)
        glds16(gsrc[i], &s_w[0][w * 4 + i][0]);
    __syncthreads();   // drains vmcnt(0): slab 0 + scale staging visible

    const short* xb  = xp + ((long)w * 64 + l) * 8;   // + ks*2048 per step
    const float* scp = &s_sc[ro * 97];
    const unsigned swz = (unsigned)((ro & 7) << 4);

    f32x4 acc = {0.f, 0.f, 0.f, 0.f};

    int cur = 0;
    for (int sl = 0; sl < NSLAB; ++sl) {
        // x fragments for this slab — issue BEFORE staging so their waitcnts
        // don't force the next-slab loads to drain.
        bf16x8 xa[SSTEP];
#pragma unroll
        for (int s = 0; s < SSTEP; ++s)
            xa[s] = *reinterpret_cast<const bf16x8*>(xb + (long)(sl * SSTEP + s) * 2048);

        // async-stage next slab into the other buffer (overlaps with compute)
        if (sl + 1 < NSLAB) {
#pragma unroll
            for (int i = 0; i < 4; ++i)
                glds16(gsrc[i] + (sl + 1) * (SLAB * 4), &s_w[cur ^ 1][w * 4 + i][0]);
        }

        const int* wl = &s_w[cur][0][0];
#pragma unroll
        for (int s = 0; s < SSTEP; ++s) {
            // byte offset within slab: row*1024 + step*128 + kq*32 (+16)
            unsigned b0 = (unsigned)((ro << 10) + (s << 7) + (kq << 5));
            const int4 qa = *reinterpret_cast<const int4*>(wl + ((b0 ^ swz) >> 2));
            const int4 qb = *reinterpret_cast<const int4*>(wl + (((b0 | 16u) ^ swz) >> 2));
            float sc = scp[sl * SSTEP + s];
            bf16x8 bfrag;
            bfrag[0] = f2bf((float)(qa.x - 128) * sc);
            bfrag[1] = f2bf((float)(qa.y - 128) * sc);
            bfrag[2] = f2bf((float)(qa.z - 128) * sc);
            bfrag[3] = f2bf((float)(qa.w - 128) * sc);
            bfrag[4] = f2bf((float)(qb.x - 128) * sc);
            bfrag[5] = f2bf((float)(qb.y - 128) * sc);
            bfrag[6] = f2bf((float)(qb.z - 128) * sc);
            bfrag[7] = f2bf((float)(qb.w - 128) * sc);
            acc = __builtin_amdgcn_mfma_f32_16x16x32_bf16(xa[s], bfrag, acc, 0, 0, 0);
        }
        __syncthreads();   // staging drained + all waves done reading buf[cur]
        cur ^= 1;
    }

    // epilogue: D col = lane&15 (=ro), row = kq*4 + r within this wave's mt
#pragma unroll
    for (int r = 0; r < 4; ++r)
        out[(long)(w * 16 + kq * 4 + r) * OUT_F + col] = acc[r] + bias;
}

extern "C" void kernel_launch(void* const* d_in, const int* in_sizes, int n_in,
                              void* d_out, int out_size, void* d_ws, size_t ws_size,
                              hipStream_t stream) {
    const float* x   = (const float*)d_in[0];
    const int*   wq  = (const int*)d_in[1];
    const float* wsc = (const float*)d_in[2];
    const int*   bq  = (const int*)d_in[3];
    const float* bs  = (const float*)d_in[4];
    float* out = (float*)d_out;

    short* xp = (short*)d_ws;   // 393216 B of ws

    pack_x<<<96, 256, 0, stream>>>(x, xp);
    gemm<<<OUT_F / 16, 256, 0, stream>>>(wq, wsc, xp, bq, bs, out);
}